// Round 6
// baseline (109.027 us; speedup 1.0000x reference)
//
#include <hip/hip_runtime.h>
#include <stdint.h>

// Problem dims
#define B_DIM 8192
#define I_DIM 512
#define O_DIM 512
#define KDIM  2048   // I_DIM * 4 features: {silu, u0, u1, u2}

// GEMM tile
#define BM 128
#define BN 64
#define BK 64        // two 32-wide halves; LDS layout [kh][rows][32]

using bf16x8 = __attribute__((ext_vector_type(8))) short;
using f32x4  = __attribute__((ext_vector_type(4))) float;

__device__ __forceinline__ unsigned short f2bf(float f) {
  union { float f; unsigned int u; } c; c.f = f;
  unsigned int x = c.u;
  unsigned int r = (x + 0x7fffu + ((x >> 16) & 1u)) >> 16;  // RNE
  return (unsigned short)r;
}

// ---------------------------------------------------------------------------
// Fused prologue. Blocks [0, 4096): A[b][i*4+{0..3}] = {silu(x), u0, u1, u2}.
// Blocks [4096, 5120): Wt[o][i*4+0]=imp*bw ; Wt[o][i*4+1+g]=(BASIS[g]·cp)*imp*sw
// ---------------------------------------------------------------------------
__global__ __launch_bounds__(256) void build_aw(const float* __restrict__ x,
                                                const float* __restrict__ cp,
                                                const float* __restrict__ bw,
                                                const float* __restrict__ sw,
                                                const float* __restrict__ imp,
                                                unsigned short* __restrict__ A,
                                                unsigned short* __restrict__ Wt) {
  if (blockIdx.x < 4096) {
    const int idx = blockIdx.x * 256 + threadIdx.x;
    const int b = idx >> 7;
    const int q = idx & 127;
    const float4 xv = *reinterpret_cast<const float4*>(x + (size_t)b * I_DIM + q * 4);
    union { unsigned short us[16]; uint4 v[2]; } out;
    const float xs[4] = {xv.x, xv.y, xv.z, xv.w};
#pragma unroll
    for (int j = 0; j < 4; ++j) {
      const float xf = xs[j];
      const float s = xf / (1.0f + __expf(-xf));          // silu, f32
      const float xc = fminf(fmaxf(xf, -1.0f), 1.0f);
      const float g = xc + 1.0f;                          // grid_idx in [0,2]
      int il = (int)floorf(g);
      if (il > 2) il = 2;
      const float fr = g - (float)il;
      int ih = il + (fr > 0.0f ? 1 : 0);
      if (ih > 2) ih = 2;
      const float u0 = (il == 0 ? 1.0f - fr : 0.0f) + (ih == 0 ? fr : 0.0f);
      const float u1 = (il == 1 ? 1.0f - fr : 0.0f) + (ih == 1 ? fr : 0.0f);
      const float u2 = (il == 2 ? 1.0f - fr : 0.0f) + (ih == 2 ? fr : 0.0f);
      out.us[j * 4 + 0] = f2bf(s);
      out.us[j * 4 + 1] = f2bf(u0);
      out.us[j * 4 + 2] = f2bf(u1);
      out.us[j * 4 + 3] = f2bf(u2);
    }
    uint4* dst = reinterpret_cast<uint4*>(A + (size_t)b * KDIM + q * 16);
    dst[0] = out.v[0];
    dst[1] = out.v[1];
  } else {
    const int idx = (blockIdx.x - 4096) * 256 + threadIdx.x;
    const int i = idx >> 9;
    const int o = idx & 511;
    const int e = i * O_DIM + o;
    const float im = imp[e];
    const float wb = im * bw[e];
    const float wsp = im * sw[e];
    const float* c = cp + (size_t)e * 5;
    const float c0 = c[0], c1 = c[1], c2 = c[2], c3 = c[3], c4 = c[4];
    const float q0 = (0.54336160f * c0 + 0.31713055f * c1 + 0.11226386f * c2 +
                      0.02410431f * c3 + 0.00313908f * c4) * wsp;
    const float q1 = (0.06493530f * c0 + 0.17651242f * c1 + 0.29101978f * c2 +
                      0.29101978f * c3 + 0.17651242f * c4) * wsp;
    const float q2 = (0.00313908f * c0 + 0.02410431f * c1 + 0.11226386f * c2 +
                      0.31713055f * c3 + 0.54336160f * c4) * wsp;
    ushort4 v;
    v.x = f2bf(wb); v.y = f2bf(q0); v.z = f2bf(q1); v.w = f2bf(q2);
    *reinterpret_cast<ushort4*>(Wt + (size_t)o * KDIM + i * 4) = v;
  }
}

// ---------------------------------------------------------------------------
// GEMM: C = A[M,K] * Wt[N,K]^T, bf16 MFMA, BK=64, 4 waves (2x2), T1 swizzle.
// Sync (T3/T4): DEPTH-3 pipeline — 3 LDS buffers, 3 tiles in flight, counted
// s_waitcnt vmcnt(12) (= oldest tile landed, 2 tiles / 12 gload_lds still
// flying). Issue-to-use distance = 2 phases (~600-800 cyc) covers L2 latency.
// Never drains vmcnt to 0 in the main loop (m218 mechanism). LDS 72 KB ->
// still 2 blocks/CU (144<=160KB), grid 512 = 2/CU -> no occupancy loss.
//   phase: WAITV(12); bar; COMPUTE(buf); bar; STAGE(buf, t+3)
// bar#1: all waves' tile-t loads landed. bar#2: buf fully read before re-stage.
// Tail waits derived: 12,12,12,6,0.
// ---------------------------------------------------------------------------
__device__ __forceinline__ void gload16(const void* g, void* lds) {
  __builtin_amdgcn_global_load_lds(
      (const __attribute__((address_space(1))) unsigned int*)g,
      (__attribute__((address_space(3))) unsigned int*)lds,
      16, 0, 0);
}

#define WAITV(n) asm volatile("s_waitcnt vmcnt(" #n ")" ::: "memory")

__global__ __launch_bounds__(256, 2) void gemm(const unsigned short* __restrict__ A,
                                               const unsigned short* __restrict__ Wt,
                                               float* __restrict__ C) {
  // [buf][kh][rows][32] elems: A 3*2*128*32, B 3*2*64*32  -> 72 KB total
  __shared__ __align__(16) unsigned short As[3 * 8192];
  __shared__ __align__(16) unsigned short Bs[3 * 4096];

  // T1: XCD-aware swizzle (8 XCDs, 512 blocks, bijective since 512%8==0).
  const int bid = blockIdx.x;
  const int nb = (bid & 7) * 64 + (bid >> 3);
  const int mt = nb >> 3;
  const int nt = nb & 7;
  const int m0 = mt * BM;
  const int n0 = nt * BN;

  const int t = threadIdx.x;
  const int l = t & 63;
  const int w = t >> 6;
  const int wm = w >> 1;     // 2 m-halves of 64 rows
  const int wn = w & 1;      // 2 n-halves of 32 cols
  const int lr = l & 15;
  const int kg = (l >> 4) * 8;

  f32x4 acc[4][2] = {};

  // Staging slot maps (LDS written linearly in slot order; per-lane GLOBAL
  // address realizes [kh][row][32] layout — m173 pattern).
  const unsigned short* gA[4];
  unsigned short* lA[3][4];
  const unsigned short* gB[2];
  unsigned short* lB[3][2];
#pragma unroll
  for (int i = 0; i < 4; ++i) {
    const int s = t + 256 * i;
    const int kh = s >> 9, row = (s >> 2) & 127, c = s & 3;
    gA[i] = A + (size_t)(m0 + row) * KDIM + kh * 32 + c * 8;
    lA[0][i] = As + s * 8;
    lA[1][i] = As + 8192 + s * 8;
    lA[2][i] = As + 16384 + s * 8;
  }
#pragma unroll
  for (int i = 0; i < 2; ++i) {
    const int s = t + 256 * i;
    const int kh = s >> 8, row = (s >> 2) & 63, c = s & 3;
    gB[i] = Wt + (size_t)(n0 + row) * KDIM + kh * 32 + c * 8;
    lB[0][i] = Bs + s * 8;
    lB[1][i] = Bs + 4096 + s * 8;
    lB[2][i] = Bs + 8192 + s * 8;
  }

  const int aoff = (wm * 64 + lr) * 32 + kg;   // + m*512 + kh*4096
  const int boff = (wn * 32 + lr) * 32 + kg;   // + n*512 + kh*2048

#define STAGE(buf, tile) do {                                                  \
    const int ko = (tile) * BK;                                                \
    _Pragma("unroll") for (int i = 0; i < 4; ++i) gload16(gA[i] + ko, lA[buf][i]); \
    _Pragma("unroll") for (int i = 0; i < 2; ++i) gload16(gB[i] + ko, lB[buf][i]); \
  } while (0)

#define COMPUTE(buf) do {                                                      \
    const unsigned short* Ab = As + (buf) * 8192;                              \
    const unsigned short* Bb = Bs + (buf) * 4096;                              \
    bf16x8 af[2][4], bfr[2][2];                                                \
    _Pragma("unroll") for (int h = 0; h < 2; ++h)                              \
      _Pragma("unroll") for (int m = 0; m < 4; ++m)                            \
        af[h][m] = *reinterpret_cast<const bf16x8*>(Ab + h * 4096 + aoff + m * 512); \
    _Pragma("unroll") for (int h = 0; h < 2; ++h)                              \
      _Pragma("unroll") for (int n = 0; n < 2; ++n)                            \
        bfr[h][n] = *reinterpret_cast<const bf16x8*>(Bb + h * 2048 + boff + n * 512); \
    _Pragma("unroll") for (int h = 0; h < 2; ++h)                              \
      _Pragma("unroll") for (int m = 0; m < 4; ++m)                            \
        _Pragma("unroll") for (int n = 0; n < 2; ++n)                          \
          acc[m][n] = __builtin_amdgcn_mfma_f32_16x16x32_bf16(af[h][m], bfr[h][n], acc[m][n], 0, 0, 0); \
  } while (0)

  // 32 K-tiles, 3 in flight. Static buf indices everywhere (rule #20).
  STAGE(0, 0);
  STAGE(1, 1);
  STAGE(2, 2);
#pragma unroll 1
  for (int tl = 0; tl < 27; tl += 3) {
    WAITV(12); __builtin_amdgcn_s_barrier();
    COMPUTE(0);
    __builtin_amdgcn_s_barrier();
    STAGE(0, tl + 3);
    WAITV(12); __builtin_amdgcn_s_barrier();
    COMPUTE(1);
    __builtin_amdgcn_s_barrier();
    STAGE(1, tl + 4);
    WAITV(12); __builtin_amdgcn_s_barrier();
    COMPUTE(2);
    __builtin_amdgcn_s_barrier();
    STAGE(2, tl + 5);
  }
  // tiles 27..31 (stages 30,31 issued here; waits 12,12,12,6,0)
  WAITV(12); __builtin_amdgcn_s_barrier();
  COMPUTE(0);                       // tile 27
  __builtin_amdgcn_s_barrier();
  STAGE(0, 30);
  WAITV(12); __builtin_amdgcn_s_barrier();
  COMPUTE(1);                       // tile 28
  __builtin_amdgcn_s_barrier();
  STAGE(1, 31);
  WAITV(12); __builtin_amdgcn_s_barrier();
  COMPUTE(2);                       // tile 29
  __builtin_amdgcn_s_barrier();
  WAITV(6); __builtin_amdgcn_s_barrier();
  COMPUTE(0);                       // tile 30
  __builtin_amdgcn_s_barrier();
  WAITV(0); __builtin_amdgcn_s_barrier();
  COMPUTE(1);                       // tile 31

#undef STAGE
#undef COMPUTE

  // Epilogue: C/D layout col = lane&15, row = (lane>>4)*4 + reg [m89]
#pragma unroll
  for (int m = 0; m < 4; ++m) {
#pragma unroll
    for (int n = 0; n < 2; ++n) {
      const int col = n0 + wn * 32 + n * 16 + lr;
      const int rbase = m0 + wm * 64 + m * 16 + (l >> 4) * 4;
#pragma unroll
      for (int r = 0; r < 4; ++r)
        C[(size_t)(rbase + r) * O_DIM + col] = acc[m][n][r];
    }
  }
}

// ---------------------------------------------------------------------------
extern "C" void kernel_launch(void* const* d_in, const int* in_sizes, int n_in,
                              void* d_out, int out_size, void* d_ws, size_t ws_size,
                              hipStream_t stream) {
  const float* x   = (const float*)d_in[0];
  const float* cp  = (const float*)d_in[1];
  const float* bw  = (const float*)d_in[2];
  const float* sw  = (const float*)d_in[3];
  const float* imp = (const float*)d_in[4];
  float* out = (float*)d_out;

  unsigned short* Abuf = (unsigned short*)d_ws;                  // 32 MB bf16
  unsigned short* Wbuf = Abuf + (size_t)B_DIM * KDIM;            //  2 MB bf16

  build_aw<<<4096 + 1024, 256, 0, stream>>>(x, cp, bw, sw, imp, Abuf, Wbuf);
  gemm<<<(B_DIM / BM) * (O_DIM / BN), 256, 0, stream>>>(Abuf, Wbuf, out);
}